// Round 2
// 160.514 us; speedup vs baseline: 1.0472x; 1.0472x over previous
//
#include <hip/hip_runtime.h>
#include <cstddef>

// Problem constants (B=4, S=2048, D=256, H=8, dh=32, d_ff=512), fp32 in/out.
constexpr int kB   = 4;
constexpr int kS   = 2048;
constexpr int kD   = 256;
constexpr int kH   = 8;
constexpr int kDH  = 32;
constexpr int kDFF = 512;
constexpr int kM   = kB * kS;   // 8192 token rows
constexpr float kEps = 1e-5f;
// 1/sqrt(32) * log2(e): scores pre-scaled so softmax uses exp2 directly.
constexpr float kScaleL2E = 0.17677669529663687f * 1.4426950408889634f;

typedef float f32x4  __attribute__((ext_vector_type(4)));
typedef short bf16x8 __attribute__((ext_vector_type(8)));
typedef unsigned short u16;
typedef unsigned int   u32;

__device__ inline u16 f2bf(float x) {
    union { float f; unsigned u; } c; c.f = x;
    const unsigned r = c.u + 0x7fffu + ((c.u >> 16) & 1u);
    return (u16)(r >> 16);
}

// pack two fp32 -> two bf16 (truncation) in ONE v_perm_b32.
// result u32: lo16 = hi16(lo), hi16 = hi16(hi)
__device__ inline u32 pk_trunc(float lo, float hi) {
    union { float f; u32 u; } a, b; a.f = lo; b.f = hi;
    return __builtin_amdgcn_perm(b.u, a.u, 0x07060302u);
}

// ---------------------------------------------------------------------------
// LayerNorm: 4 rows/block, one wave per row, 4 floats/lane, pure-shuffle
// reduction. bf16 out. (R6-proven.)
// ---------------------------------------------------------------------------
__global__ __launch_bounds__(256)
void ln_kernel(const float* __restrict__ x, const float* __restrict__ g,
               const float* __restrict__ b, u16* __restrict__ y)
{
    const int wave = threadIdx.x >> 6;
    const int lane = threadIdx.x & 63;
    const int row  = blockIdx.x * 4 + wave;
    const float4 v = *(const float4*)&x[(size_t)row * kD + lane * 4];
    float s1 = (v.x + v.y) + (v.z + v.w);
    float s2 = (v.x * v.x + v.y * v.y) + (v.z * v.z + v.w * v.w);
    #pragma unroll
    for (int off = 1; off < 64; off <<= 1) {
        s1 += __shfl_xor(s1, off);
        s2 += __shfl_xor(s2, off);
    }
    const float mu  = s1 * (1.0f / kD);
    const float var = s2 * (1.0f / kD) - mu * mu;
    const float inv = rsqrtf(var + kEps);
    const float4 g4 = *(const float4*)&g[lane * 4];
    const float4 b4 = *(const float4*)&b[lane * 4];
    *(ushort4*)&y[(size_t)row * kD + lane * 4] = make_ushort4(
        f2bf((v.x - mu) * inv * g4.x + b4.x),
        f2bf((v.y - mu) * inv * g4.y + b4.y),
        f2bf((v.z - mu) * inv * g4.z + b4.z),
        f2bf((v.w - mu) * inv * g4.w + b4.w));
}

// ---------------------------------------------------------------------------
// bf16 MFMA NT GEMM, M-pair fused K-loop: C = A @ W.T (+bias).
// Block tile 128(M) x NT(N), 4 waves; wave w owns rows [m0+16w,+16) AND
// [m0+64+16w,+16). Each staged B-fragment read feeds TWO MFMAs (one per
// m-half): per k-step = 2 A global loads + NT/16 ds_read_b128 + 2*(NT/16)
// MFMAs -> LDS:MFMA cycle ratio ~48:38 instead of 48:19 (was LDS-bound 2.5x).
// W fp32 cast to bf16 during linear coalesced LDS staging (once per block).
// LDS stride KTOT+4 (2-way bank aliasing = free).
// OUTMODE: 0 = fp32 (+RES), 1 = SiLU->bf16, 2 = QKV split:
//   Qb[bh][s][dh] (pre-scaled kScaleL2E), Kb[bh][s][dh],
//   Vp = quad-interleaved V: within a 32-key block, key so -> slot
//   (vq=(so>>2)&3, vj=(so&3)|(((so>>4)&1)<<2)), stored [bh][s/32][vq][dh][8].
// ---------------------------------------------------------------------------
template<int NT, int OUTMODE, bool RES, int KTOT>
__global__ __launch_bounds__(256)
void gemm_bf16(const u16* __restrict__ A, const float* __restrict__ Wf,
               const float* __restrict__ bias, const float* __restrict__ res,
               float* __restrict__ Cf, u16* __restrict__ Cb,
               u16* __restrict__ KbP, u16* __restrict__ VtP, int N)
{
    constexpr int BSTR = KTOT + 4;
    __shared__ u16 Bs[NT * BSTR];
    const int tid  = threadIdx.x;
    const int wave = tid >> 6;
    const int lane = tid & 63;
    const int quad = lane >> 4;
    const int l16  = lane & 15;
    const int m0 = blockIdx.x * 128;
    const int n0 = blockIdx.y * NT;

    // ---- stage W[n0:n0+NT, :] fp32 -> bf16, linear & coalesced (once) ----
    {
        constexpr int ITS = (NT * KTOT) / 1024;
        #pragma unroll
        for (int it = 0; it < ITS; ++it) {
            const int e   = it * 1024 + tid * 4;
            const int row = e / KTOT;
            const int col = e & (KTOT - 1);
            const float4 wv = *(const float4*)&Wf[(size_t)(n0 + row) * KTOT + col];
            *(ushort4*)&Bs[row * BSTR + col] = make_ushort4(
                f2bf(wv.x), f2bf(wv.y), f2bf(wv.z), f2bf(wv.w));
        }
    }
    __syncthreads();

    f32x4 acc[2][NT / 16];
    #pragma unroll
    for (int mt = 0; mt < 2; ++mt)
        #pragma unroll
        for (int ni = 0; ni < NT / 16; ++ni) acc[mt][ni] = {0.f, 0.f, 0.f, 0.f};

    const u16* arow0 = &A[(size_t)(m0 + wave * 16 + l16) * KTOT];
    const u16* arow1 = &A[(size_t)(m0 + 64 + wave * 16 + l16) * KTOT];
    #pragma unroll 4
    for (int k0 = 0; k0 < KTOT; k0 += 32) {
        const bf16x8 a0 = *(const bf16x8*)&arow0[k0 + quad * 8];
        const bf16x8 a1 = *(const bf16x8*)&arow1[k0 + quad * 8];
        #pragma unroll
        for (int ni = 0; ni < NT / 16; ++ni) {
            const bf16x8 bf = *(const bf16x8*)&Bs[(ni * 16 + l16) * BSTR + k0 + quad * 8];
            acc[0][ni] = __builtin_amdgcn_mfma_f32_16x16x32_bf16(a0, bf, acc[0][ni], 0, 0, 0);
            acc[1][ni] = __builtin_amdgcn_mfma_f32_16x16x32_bf16(a1, bf, acc[1][ni], 0, 0, 0);
        }
    }

    // ---- epilogue (both m-halves) ----
    #pragma unroll
    for (int mt = 0; mt < 2; ++mt) {
        #pragma unroll
        for (int ni = 0; ni < NT / 16; ++ni) {
            const float bias_v = bias[n0 + ni * 16 + l16];
            #pragma unroll
            for (int r = 0; r < 4; ++r) {
                const int m = m0 + mt * 64 + wave * 16 + quad * 4 + r;
                float v = acc[mt][ni][r] + bias_v;
                if (OUTMODE == 0) {
                    const int n = n0 + ni * 16 + l16;
                    if (RES) v += res[(size_t)m * N + n];
                    Cf[(size_t)m * N + n] = v;
                } else if (OUTMODE == 1) {
                    const int n = n0 + ni * 16 + l16;
                    v = v / (1.0f + __expf(-v));
                    Cb[(size_t)m * N + n] = f2bf(v);
                } else {
                    const int rgn = n0 >> 8;               // 0=Q 1=K 2=V
                    const int nl  = (n0 & 255) + ni * 16 + l16;
                    const int hh  = nl >> 5, dh = nl & 31;
                    const int bb  = m >> 11, s = m & (kS - 1);
                    const int bh  = bb * kH + hh;
                    if (rgn == 0)
                        Cb[((size_t)bh * kS + s) * kDH + dh] = f2bf(v * kScaleL2E);
                    else if (rgn == 1)
                        KbP[((size_t)bh * kS + s) * kDH + dh] = f2bf(v);
                    else {
                        // quad-interleave within 32-key block
                        const int so = s & 31;
                        const int vq = (so >> 2) & 3;
                        const int vj = (so & 3) | (((so >> 4) & 1) << 2);
                        VtP[(((size_t)bh * (kS / 32) + (s >> 5)) * 4 + vq) * 256
                            + dh * 8 + vj] = f2bf(v);
                    }
                }
            }
        }
    }
}

// ---------------------------------------------------------------------------
// MFMA flash attention v15 = v14 with:
//   * 64 queries per wave (4 q-fragments) -> each K/V fragment load feeds 4
//     S-MFMAs instead of 2: halves global K/V fetch (512MB -> 256MB L2/L3).
//   * softmax denominator via ones-column MFMA: lsum = mfma(P, 1s) puts the
//     per-query partial denominators in the SAME (quad*4+r) register layout
//     the combine uses -> removes the 30-add lp tree AND all end shuffles
//     from the VALU-bound loop (moved onto the underused MFMA pipe).
//   * paired-tile explicit load-ahead: both tiles' kf/vf issued before either
//     tile's compute, so the second tile never stalls on L2 latency.
// Block = 4 waves: (qsub=wave>>1)*64 queries x (half=wave&1)*1024 keys,
// 128 queries/block of one (b,h). Grid (kS/128=16, 8, 4) = 512 blocks.
// ---------------------------------------------------------------------------
__global__ __launch_bounds__(256)
void attn_kernel(const u16* __restrict__ Qb, const u16* __restrict__ Kb,
                 const u16* __restrict__ Vp, u16* __restrict__ ctx)
{
    __shared__ float cbuf[2][64 * 33];     // combine buffer only (16.9 KB)
    const int tid  = threadIdx.x;
    const int wave = tid >> 6;
    const int lane = tid & 63;
    const int quad = lane >> 4;
    const int l16  = lane & 15;
    const int h = blockIdx.y;
    const int b = blockIdx.z;
    const int bh = b * kH + h;
    const int qsub = wave >> 1;
    const int half = wave & 1;
    const int q0 = blockIdx.x * 128 + qsub * 64;

    // Q fragments double as MFMA B-operands (B[k=dh=quad*8+j][n=query=l16]).
    bf16x8 aq[4];
    #pragma unroll
    for (int qb = 0; qb < 4; ++qb)
        aq[qb] = *(const bf16x8*)
            &Qb[((size_t)bh * kS + q0 + qb * 16 + l16) * kDH + quad * 8];

    const u16* Kbase = Kb + (size_t)bh * kS * kDH;
    const u16* Vbase = Vp + (size_t)bh * (kS * 32);   // (kS/32)*4*256 u16 per bh

    f32x4 O[4][2] = {};
    f32x4 lsum[4] = {};
    const f32x4 zz = {0.f, 0.f, 0.f, 0.f};
    union { u32 u[4]; bf16x8 v; } ones;
    ones.u[0] = ones.u[1] = ones.u[2] = ones.u[3] = 0x3F803F80u;  // bf16 1.0 x8

    auto load_tile = [&](int kt, bf16x8 (&kf)[4], bf16x8 (&vf)[2][2]) {
        // K A-frags: natural key order, coalesced (A[m=key=l16][k=dh]).
        #pragma unroll
        for (int kg = 0; kg < 4; ++kg)
            kf[kg] = *(const bf16x8*)
                &Kbase[(size_t)(kt + kg * 16 + l16) * kDH + quad * 8];
        // V B-frags: quad-interleaved layout -> contiguous 16-B per lane.
        #pragma unroll
        for (int ks = 0; ks < 2; ++ks)
            #pragma unroll
            for (int nf = 0; nf < 2; ++nf)
                vf[ks][nf] = *(const bf16x8*)
                    &Vbase[(size_t)(((kt >> 5) + ks) * 4 + quad) * 1024
                           + (nf * 16 + l16) * 8];
    };

    auto comp_tile = [&](bf16x8 (&kf)[4], bf16x8 (&vf)[2][2]) {
        #pragma unroll
        for (int qb = 0; qb < 4; ++qb) {
            // S^T[key][query]: operand-swapped MFMA.
            f32x4 S0 = __builtin_amdgcn_mfma_f32_16x16x32_bf16(kf[0], aq[qb], zz, 0, 0, 0);
            f32x4 S1 = __builtin_amdgcn_mfma_f32_16x16x32_bf16(kf[1], aq[qb], zz, 0, 0, 0);
            f32x4 S2 = __builtin_amdgcn_mfma_f32_16x16x32_bf16(kf[2], aq[qb], zz, 0, 0, 0);
            f32x4 S3 = __builtin_amdgcn_mfma_f32_16x16x32_bf16(kf[3], aq[qb], zz, 0, 0, 0);

            // raw v_exp_f32 + in-register pack into PV A-frags.
            union { u32 u[4]; bf16x8 v; } pA0, pA1;
            pA0.u[0] = pk_trunc(__builtin_amdgcn_exp2f(S0[0]), __builtin_amdgcn_exp2f(S0[1]));
            pA0.u[1] = pk_trunc(__builtin_amdgcn_exp2f(S0[2]), __builtin_amdgcn_exp2f(S0[3]));
            pA0.u[2] = pk_trunc(__builtin_amdgcn_exp2f(S1[0]), __builtin_amdgcn_exp2f(S1[1]));
            pA0.u[3] = pk_trunc(__builtin_amdgcn_exp2f(S1[2]), __builtin_amdgcn_exp2f(S1[3]));
            pA1.u[0] = pk_trunc(__builtin_amdgcn_exp2f(S2[0]), __builtin_amdgcn_exp2f(S2[1]));
            pA1.u[1] = pk_trunc(__builtin_amdgcn_exp2f(S2[2]), __builtin_amdgcn_exp2f(S2[3]));
            pA1.u[2] = pk_trunc(__builtin_amdgcn_exp2f(S3[0]), __builtin_amdgcn_exp2f(S3[1]));
            pA1.u[3] = pk_trunc(__builtin_amdgcn_exp2f(S3[2]), __builtin_amdgcn_exp2f(S3[3]));

            // denominator on the MFMA pipe: lsum[qb][r] = partial denom of
            // query qb*16+quad*4+r (same row mapping as O's C-layout).
            lsum[qb] = __builtin_amdgcn_mfma_f32_16x16x32_bf16(pA0.v, ones.v, lsum[qb], 0, 0, 0);
            lsum[qb] = __builtin_amdgcn_mfma_f32_16x16x32_bf16(pA1.v, ones.v, lsum[qb], 0, 0, 0);

            O[qb][0] = __builtin_amdgcn_mfma_f32_16x16x32_bf16(pA0.v, vf[0][0], O[qb][0], 0, 0, 0);
            O[qb][1] = __builtin_amdgcn_mfma_f32_16x16x32_bf16(pA0.v, vf[0][1], O[qb][1], 0, 0, 0);
            O[qb][0] = __builtin_amdgcn_mfma_f32_16x16x32_bf16(pA1.v, vf[1][0], O[qb][0], 0, 0, 0);
            O[qb][1] = __builtin_amdgcn_mfma_f32_16x16x32_bf16(pA1.v, vf[1][1], O[qb][1], 0, 0, 0);
        }
    };

    const int kbeg = half * (kS / 2);
    #pragma unroll 1
    for (int t2 = 0; t2 < 8; ++t2) {
        const int ktA = kbeg + t2 * 128;
        bf16x8 kfA[4], vfA[2][2], kfB[4], vfB[2][2];
        load_tile(ktA,      kfA, vfA);
        load_tile(ktA + 64, kfB, vfB);   // issued before tile-A compute
        comp_tile(kfA, vfA);
        comp_tile(kfB, vfB);
    }

    // ---- combine the two key-halves of each 64-query sub-block ----
    float* cb = cbuf[qsub];
    if (half == 1) {
        #pragma unroll
        for (int qb = 0; qb < 4; ++qb)
            #pragma unroll
            for (int r = 0; r < 4; ++r) {
                const int row = qb * 16 + quad * 4 + r;
                cb[row * 33 + l16]      = O[qb][0][r];
                cb[row * 33 + 16 + l16] = O[qb][1][r];
                if (l16 == 0)
                    cb[row * 33 + 32] = lsum[qb][r];
            }
    }
    __syncthreads();
    if (half == 0) {
        #pragma unroll
        for (int qb = 0; qb < 4; ++qb)
            #pragma unroll
            for (int r = 0; r < 4; ++r) {
                const int row = qb * 16 + quad * 4 + r;
                const float lq  = lsum[qb][r] + cb[row * 33 + 32];
                const float inv = 1.0f / lq;
                const float o0 = O[qb][0][r] + cb[row * 33 + l16];
                const float o1 = O[qb][1][r] + cb[row * 33 + 16 + l16];
                const int q = q0 + row;
                u16* crow = ctx + ((size_t)(b * kS + q)) * kD + h * kDH;
                crow[l16]      = f2bf(o0 * inv);
                crow[16 + l16] = f2bf(o1 * inv);
            }
    }
}

// ---------------------------------------------------------------------------
// 7 dispatches: ln1 -> qkv -> attn -> proj(+res) -> ln2 -> ffn1(SiLU) ->
// ffn2(+res). Workspace (bytes):
//   [ 0M, 4M)  Qb   (bf16)  -- [0,8M) reused as h after attn
//   [ 4M, 8M)  Kb   (bf16)
//   [ 8M,12M)  Vp   (bf16, quad-interleaved)
//   [12M,16M)  ctx  (bf16)
//   [16M,20M)  y    (bf16, LN1 then LN2)
// ---------------------------------------------------------------------------
extern "C" void kernel_launch(void* const* d_in, const int* in_sizes, int n_in,
                              void* d_out, int out_size, void* d_ws, size_t ws_size,
                              hipStream_t stream)
{
    const float* x      = (const float*)d_in[0];
    const float* ln1_g  = (const float*)d_in[1];
    const float* ln1_b  = (const float*)d_in[2];
    const float* w_qkv  = (const float*)d_in[3];
    const float* b_qkv  = (const float*)d_in[4];
    const float* w_proj = (const float*)d_in[5];
    const float* b_proj = (const float*)d_in[6];
    const float* ln2_g  = (const float*)d_in[7];
    const float* ln2_b  = (const float*)d_in[8];
    const float* w1     = (const float*)d_in[9];
    const float* b1     = (const float*)d_in[10];
    const float* w2     = (const float*)d_in[11];
    const float* b2     = (const float*)d_in[12];
    float* out = (float*)d_out;

    char* ws = (char*)d_ws;
    u16* Qb  = (u16*)ws;
    u16* Kb  = (u16*)(ws + ((size_t)4  << 20));
    u16* Vp  = (u16*)(ws + ((size_t)8  << 20));
    u16* ctx = (u16*)(ws + ((size_t)12 << 20));
    u16* y   = (u16*)(ws + ((size_t)16 << 20));
    u16* h   = (u16*)ws;                     // aliases Qb/Kb (dead after attn)

    const dim3 blk(256);

    // 1) y = bf16(LN1(x))
    ln_kernel<<<dim3(kM / 4), blk, 0, stream>>>(x, ln1_g, ln1_b, y);
    // 2) Qb/Kb/Vp = bf16(y @ w_qkv.T + b_qkv), Q pre-scaled, V interleaved
    gemm_bf16<64, 2, false, 256><<<dim3(kM / 128, 12), blk, 0, stream>>>(
        y, w_qkv, b_qkv, nullptr, nullptr, Qb, Kb, Vp, 0);
    // 3) ctx = attention (bf16 out), in-register P, 64q/wave
    attn_kernel<<<dim3(kS / 128, kH, kB), blk, 0, stream>>>(Qb, Kb, Vp, ctx);
    // 4) out = x + ctx @ w_proj.T + b_proj   (fp32)
    gemm_bf16<32, 0, true, 256><<<dim3(kM / 128, kD / 32), blk, 0, stream>>>(
        ctx, w_proj, b_proj, x, out, nullptr, nullptr, nullptr, kD);
    // 5) y = bf16(LN2(out))
    ln_kernel<<<dim3(kM / 4), blk, 0, stream>>>(out, ln2_g, ln2_b, y);
    // 6) h = bf16(silu(y @ w1.T + b1))
    gemm_bf16<64, 1, false, 256><<<dim3(kM / 128, kDFF / 64), blk, 0, stream>>>(
        y, w1, b1, nullptr, nullptr, h, nullptr, nullptr, kDFF);
    // 7) out = out + h @ w2.T + b2   (fp32, K=512; N = output stride = kD!)
    gemm_bf16<32, 0, true, 512><<<dim3(kM / 128, kD / 32), blk, 0, stream>>>(
        h, w2, b2, out, out, nullptr, nullptr, nullptr, kD);
}